// Round 7
// baseline (861.293 us; speedup 1.0000x reference)
//
#include <hip/hip_runtime.h>
#include <math.h>

__device__ __forceinline__ float silu_f(float x) {
    return x / (1.0f + __expf(-x));
}

// sin/cos of 2*pi*rev using the HW units (input in REVOLUTIONS, fract-reduced).
__device__ __forceinline__ void sincos_2pi_rev(float rev, float& s, float& c) {
#if __has_builtin(__builtin_amdgcn_sinf) && __has_builtin(__builtin_amdgcn_cosf)
    const float fr = rev - floorf(rev);     // [0,1) -> v_fract
    s = __builtin_amdgcn_sinf(fr);          // v_sin_f32: sin(2*pi*fr)
    c = __builtin_amdgcn_cosf(fr);          // v_cos_f32
#else
    const float xp = 6.2831853071795864769f * rev;
    s = sinf(xp); c = cosf(xp);
#endif
}

// Per-edge MLP core. Weight pointers are wave-uniform -> scalar loads (SGPR).
__device__ __forceinline__ void edge_core(
    const float* __restrict__ coord,
    const float* __restrict__ node_feat,
    const float* __restrict__ ff_coeff,
    const float* __restrict__ ew1, const float* __restrict__ eb1,
    const float* __restrict__ ew2, const float* __restrict__ eb2,
    const float* __restrict__ cw1, const float* __restrict__ cb1,
    const float* __restrict__ cw2,
    int i, int j,
    float* __restrict__ m,           // out [32]
    float& cdx, float& cdy, float& cdz, float& w)
{
    const float cix = coord[3*(size_t)i+0], ciy = coord[3*(size_t)i+1], ciz = coord[3*(size_t)i+2];
    const float cjx = coord[3*(size_t)j+0], cjy = coord[3*(size_t)j+1], cjz = coord[3*(size_t)j+2];
    cdx = cix - cjx; cdy = ciy - cjy; cdz = ciz - cjz;
    const float radial = cdx*cdx + cdy*cdy + cdz*cdz;

    // Fourier features: reference computes sin/cos(2*pi*(radial*coeff)).
    // In revolutions that's just radial*coeff -> v_fract + v_sin/v_cos.
    float ff[8];
    #pragma unroll
    for (int k = 0; k < 4; ++k) {
        float s, c;
        sincos_2pi_rev(radial * ff_coeff[k], s, c);
        ff[k]     = c;
        ff[4 + k] = s;
    }

    // ---- edge MLP layer 1: in[72] @ ew1[72,32] + eb1 ----
    float acc[32];
    #pragma unroll
    for (int o = 0; o < 32; ++o) acc[o] = eb1[o];

    {
        const float4* nfi4 = reinterpret_cast<const float4*>(node_feat + (size_t)i * 32);
        for (int q = 0; q < 8; ++q) {           // runtime loop: bounded code size
            float4 v = nfi4[q];
            float xs[4] = {v.x, v.y, v.z, v.w};
            const float* wr = ew1 + q * 4 * 32;
            #pragma unroll
            for (int kk = 0; kk < 4; ++kk) {
                #pragma unroll
                for (int o = 0; o < 32; ++o)
                    acc[o] = fmaf(xs[kk], wr[kk*32 + o], acc[o]);
            }
        }
        const float4* nfj4 = reinterpret_cast<const float4*>(node_feat + (size_t)j * 32);
        for (int q = 0; q < 8; ++q) {
            float4 v = nfj4[q];
            float xs[4] = {v.x, v.y, v.z, v.w};
            const float* wr = ew1 + (32 + q * 4) * 32;
            #pragma unroll
            for (int kk = 0; kk < 4; ++kk) {
                #pragma unroll
                for (int o = 0; o < 32; ++o)
                    acc[o] = fmaf(xs[kk], wr[kk*32 + o], acc[o]);
            }
        }
        #pragma unroll
        for (int k = 0; k < 8; ++k) {
            const float* wr = ew1 + (64 + k) * 32;
            #pragma unroll
            for (int o = 0; o < 32; ++o)
                acc[o] = fmaf(ff[k], wr[o], acc[o]);
        }
    }

    float m1[32];
    #pragma unroll
    for (int o = 0; o < 32; ++o) m1[o] = silu_f(acc[o]);

    // ---- edge MLP layer 2 ----
    #pragma unroll
    for (int o = 0; o < 32; ++o) m[o] = eb2[o];
    #pragma unroll
    for (int h = 0; h < 32; ++h) {
        #pragma unroll
        for (int o = 0; o < 32; ++o)
            m[o] = fmaf(m1[h], ew2[h*32 + o], m[o]);
    }
    #pragma unroll
    for (int o = 0; o < 32; ++o) m[o] = silu_f(m[o]);

    // ---- coord head ----
    float c1[32];
    #pragma unroll
    for (int o = 0; o < 32; ++o) c1[o] = cb1[o];
    #pragma unroll
    for (int h = 0; h < 32; ++h) {
        #pragma unroll
        for (int o = 0; o < 32; ++o)
            c1[o] = fmaf(m[h], cw1[h*32 + o], c1[o]);
    }
    w = 0.0f;
    #pragma unroll
    for (int o = 0; o < 32; ++o) w += silu_f(c1[o]) * cw2[o];
}

// ================= CSR (direct-slot) path =================

// K0: histogram of destination node per edge.
__global__ __launch_bounds__(256) void egc_hist(
    const int* __restrict__ idx_i, int* __restrict__ counts, int E)
{
    const int e = blockIdx.x * 256 + threadIdx.x;
    if (e < E) atomicAdd(&counts[idx_i[e]], 1);   // fire-and-forget
}

// K1: single-workgroup exclusive scan counts[N] -> row_start[N+1], cursor=row_start.
__global__ __launch_bounds__(1024) void egc_scan(
    const int* __restrict__ counts, int* __restrict__ row_start,
    int* __restrict__ cursor, int N)
{
    __shared__ int wsum[16];
    __shared__ int carry_s;
    const int tid = threadIdx.x;
    const int lane = tid & 63, wid = tid >> 6;
    if (tid == 0) carry_s = 0;
    __syncthreads();
    for (int base = 0; base < N; base += 1024) {
        const int idx = base + tid;
        const int x = (idx < N) ? counts[idx] : 0;
        int incl = x;
        #pragma unroll
        for (int off = 1; off < 64; off <<= 1) {
            int v = __shfl_up(incl, off, 64);
            if (lane >= off) incl += v;
        }
        if (lane == 63) wsum[wid] = incl;
        __syncthreads();
        if (wid == 0) {
            int v = (lane < 16) ? wsum[lane] : 0;
            int s = v;
            #pragma unroll
            for (int off = 1; off < 16; off <<= 1) {
                int t = __shfl_up(s, off, 64);
                if (lane >= off) s += t;
            }
            if (lane < 16) wsum[lane] = s - v;   // exclusive wave offsets
        }
        __syncthreads();
        const int carry = carry_s;
        if (idx < N) {
            const int v = carry + wsum[wid] + incl - x;
            row_start[idx] = v;
            cursor[idx]    = v;
        }
        __syncthreads();
        if (tid == 1023) carry_s = carry + wsum[15] + incl;  // + chunk total
        __syncthreads();
    }
    if (tid == 0) row_start[N] = carry_s;
}

// K2: per-edge compute; claim CSR slot early (latency hidden under MLP).
// m goes directly into CSR order (128B full-line rows). trans stays in
// e-order (streaming full-line writes); eord[slot]=e provides the map
// (4B scattered into a 6.4MB L2-resident buffer -> no HBM RMW).
__global__ __launch_bounds__(256) void egc_edge_direct(
    const float* __restrict__ coord,
    const float* __restrict__ node_feat,
    const int*   __restrict__ edge_index,
    const float* __restrict__ ff_coeff,
    const float* __restrict__ ew1, const float* __restrict__ eb1,
    const float* __restrict__ ew2, const float* __restrict__ eb2,
    const float* __restrict__ cw1, const float* __restrict__ cb1,
    const float* __restrict__ cw2,
    int*   __restrict__ cursor,   // [N], pre-initialized to row_start
    float* __restrict__ m_buf,    // [E,32] in CSR order
    float* __restrict__ trans4,   // [E,4]  in e-order
    int*   __restrict__ eord,     // [E]    slot -> e
    int E)
{
    const int e = blockIdx.x * 256 + threadIdx.x;
    if (e >= E) return;

    const int i = edge_index[e];
    const int j = edge_index[E + e];
    const int slot = atomicAdd(&cursor[i], 1);   // early; used only at stores

    float m[32], cdx, cdy, cdz, w;
    edge_core(coord, node_feat, ff_coeff, ew1, eb1, ew2, eb2, cw1, cb1, cw2,
              i, j, m, cdx, cdy, cdz, w);

    float4* mb = reinterpret_cast<float4*>(m_buf + (size_t)slot * 32);
    #pragma unroll
    for (int q = 0; q < 8; ++q) {
        float4 v;
        v.x = m[4*q+0]; v.y = m[4*q+1]; v.z = m[4*q+2]; v.w = m[4*q+3];
        mb[q] = v;
    }
    float4 t; t.x = cdx * w; t.y = cdy * w; t.z = cdz * w; t.w = 0.0f;
    *reinterpret_cast<float4*>(trans4 + (size_t)e * 4) = t;   // streaming
    eord[slot] = e;
}

// K3: wave-parallel node kernel — 32 lanes per node, 8 nodes per 256-block.
// Gather: one coalesced 128B m_buf row per iteration. MLP: shfl broadcasts
// + coalesced weight-row loads (L1-resident).
__global__ __launch_bounds__(256) void egc_node_wave(
    const float* __restrict__ coord,
    const float* __restrict__ node_feat,
    const float* __restrict__ m_buf,
    const float* __restrict__ trans4,
    const int*   __restrict__ eord,
    const int*   __restrict__ row_start,
    const float* __restrict__ nw1, const float* __restrict__ nb1,
    const float* __restrict__ nw2, const float* __restrict__ nb2,
    float* __restrict__ out_node,   // [N,32]
    float* __restrict__ out_coord,  // [N,3]
    int N)
{
    const int tid = threadIdx.x;
    const int l32 = tid & 31;
    const int n = blockIdx.x * 8 + (tid >> 5);
    if (n >= N) return;

    const int rs = row_start[n];
    const int re = row_start[n + 1];

    float agg = 0.0f;   // this lane's feature dim
    float tr  = 0.0f;   // lanes 0..2 accumulate x/y/z
    for (int k = rs; k < re; ++k) {
        agg += m_buf[(size_t)k * 32 + l32];
        if (l32 < 3) {
            const int e = eord[k];
            tr += trans4[(size_t)e * 4 + l32];
        }
    }

    const float nf = node_feat[(size_t)n * 32 + l32];

    // h1 = silu([nf, agg] @ nw1 + nb1)
    float acc = nb1[l32];
    #pragma unroll
    for (int k = 0; k < 32; ++k)
        acc = fmaf(__shfl(nf, k, 32), nw1[k*32 + l32], acc);
    #pragma unroll
    for (int k = 0; k < 32; ++k)
        acc = fmaf(__shfl(agg, k, 32), nw1[(32+k)*32 + l32], acc);
    const float h1 = silu_f(acc);

    float h2 = nb2[l32];
    #pragma unroll
    for (int k = 0; k < 32; ++k)
        h2 = fmaf(__shfl(h1, k, 32), nw2[k*32 + l32], h2);

    out_node[(size_t)n * 32 + l32] = nf + h2;

    if (l32 < 3) {
        const float deg = (float)(re - rs);
        out_coord[(size_t)n * 3 + l32] =
            coord[(size_t)n * 3 + l32] + tr / fmaxf(deg, 1.0f);
    }
}

// ================= fallback (atomic) path =================

__global__ __launch_bounds__(256) void egc_edge_fb(
    const float* __restrict__ coord,
    const float* __restrict__ node_feat,
    const int*   __restrict__ edge_index,
    const float* __restrict__ ff_coeff,
    const float* __restrict__ ew1, const float* __restrict__ eb1,
    const float* __restrict__ ew2, const float* __restrict__ eb2,
    const float* __restrict__ cw1, const float* __restrict__ cb1,
    const float* __restrict__ cw2,
    float* __restrict__ agg_h, float* __restrict__ agg_c, float* __restrict__ counts,
    int E)
{
    const int e = blockIdx.x * 256 + threadIdx.x;
    if (e >= E) return;
    const int i = edge_index[e];
    const int j = edge_index[E + e];

    float m[32], cdx, cdy, cdz, w;
    edge_core(coord, node_feat, ff_coeff, ew1, eb1, ew2, eb2, cw1, cb1, cw2,
              i, j, m, cdx, cdy, cdz, w);

    float* dst = agg_h + (size_t)i * 32;
    #pragma unroll
    for (int o = 0; o < 32; ++o) atomicAdd(&dst[o], m[o]);
    atomicAdd(&agg_c[(size_t)i*3 + 0], cdx * w);
    atomicAdd(&agg_c[(size_t)i*3 + 1], cdy * w);
    atomicAdd(&agg_c[(size_t)i*3 + 2], cdz * w);
    atomicAdd(&counts[i], 1.0f);
}

__global__ __launch_bounds__(256) void egc_node_fb(
    const float* __restrict__ coord,
    const float* __restrict__ node_feat,
    const float* __restrict__ agg_h,
    const float* __restrict__ agg_c,
    const float* __restrict__ counts,
    const float* __restrict__ nw1, const float* __restrict__ nb1,
    const float* __restrict__ nw2, const float* __restrict__ nb2,
    float* __restrict__ out_node, float* __restrict__ out_coord, int N)
{
    const int n = blockIdx.x * 256 + threadIdx.x;
    if (n >= N) return;

    float nf[32];
    {
        const float4* nf4 = reinterpret_cast<const float4*>(node_feat + (size_t)n * 32);
        #pragma unroll
        for (int q = 0; q < 8; ++q) {
            float4 v = nf4[q];
            nf[4*q+0] = v.x; nf[4*q+1] = v.y; nf[4*q+2] = v.z; nf[4*q+3] = v.w;
        }
    }
    float acc[32];
    #pragma unroll
    for (int o = 0; o < 32; ++o) acc[o] = nb1[o];
    #pragma unroll
    for (int k = 0; k < 32; ++k) {
        #pragma unroll
        for (int o = 0; o < 32; ++o)
            acc[o] = fmaf(nf[k], nw1[k*32 + o], acc[o]);
    }
    {
        const float4* ah4 = reinterpret_cast<const float4*>(agg_h + (size_t)n * 32);
        #pragma unroll
        for (int q = 0; q < 8; ++q) {
            float4 v = ah4[q];
            float xs[4] = {v.x, v.y, v.z, v.w};
            const float* wr = nw1 + (32 + q * 4) * 32;
            #pragma unroll
            for (int kk = 0; kk < 4; ++kk) {
                #pragma unroll
                for (int o = 0; o < 32; ++o)
                    acc[o] = fmaf(xs[kk], wr[kk*32 + o], acc[o]);
            }
        }
    }
    float h1[32];
    #pragma unroll
    for (int o = 0; o < 32; ++o) h1[o] = silu_f(acc[o]);
    float h2[32];
    #pragma unroll
    for (int o = 0; o < 32; ++o) h2[o] = nb2[o];
    #pragma unroll
    for (int k = 0; k < 32; ++k) {
        #pragma unroll
        for (int o = 0; o < 32; ++o)
            h2[o] = fmaf(h1[k], nw2[k*32 + o], h2[o]);
    }
    {
        float4* on4 = reinterpret_cast<float4*>(out_node + (size_t)n * 32);
        #pragma unroll
        for (int q = 0; q < 8; ++q) {
            float4 v;
            v.x = nf[4*q+0] + h2[4*q+0];
            v.y = nf[4*q+1] + h2[4*q+1];
            v.z = nf[4*q+2] + h2[4*q+2];
            v.w = nf[4*q+3] + h2[4*q+3];
            on4[q] = v;
        }
    }
    const float cnt = fmaxf(counts[n], 1.0f);
    const float inv = 1.0f / cnt;
    out_coord[(size_t)n*3 + 0] = coord[(size_t)n*3 + 0] + agg_c[(size_t)n*3 + 0] * inv;
    out_coord[(size_t)n*3 + 1] = coord[(size_t)n*3 + 1] + agg_c[(size_t)n*3 + 1] * inv;
    out_coord[(size_t)n*3 + 2] = coord[(size_t)n*3 + 2] + agg_c[(size_t)n*3 + 2] * inv;
}

// ================= launch =================

extern "C" void kernel_launch(void* const* d_in, const int* in_sizes, int n_in,
                              void* d_out, int out_size, void* d_ws, size_t ws_size,
                              hipStream_t stream) {
    const float* coord     = (const float*)d_in[0];
    const float* node_feat = (const float*)d_in[1];
    const int*   edge_index= (const int*)  d_in[2];
    const float* ff_coeff  = (const float*)d_in[3];
    const float* ew1 = (const float*)d_in[4];
    const float* eb1 = (const float*)d_in[5];
    const float* ew2 = (const float*)d_in[6];
    const float* eb2 = (const float*)d_in[7];
    const float* cw1 = (const float*)d_in[8];
    const float* cb1 = (const float*)d_in[9];
    const float* cw2 = (const float*)d_in[10];
    const float* nw1 = (const float*)d_in[11];
    const float* nb1 = (const float*)d_in[12];
    const float* nw2 = (const float*)d_in[13];
    const float* nb2 = (const float*)d_in[14];

    const int N = in_sizes[0] / 3;   // coord [N,3]
    const int E = in_sizes[2] / 2;   // edge_index [2,E]

    float* out_node  = (float*)d_out;             // [N,32]
    float* out_coord = out_node + (size_t)N * 32; // [N,3]

    // workspace layout (element offsets, all 16B-aligned)
    const size_t m_off   = 0;                          // E*32 floats
    const size_t t_off   = m_off + (size_t)E * 32;     // E*4 floats
    const size_t eo_off  = t_off + (size_t)E * 4;      // E ints
    const size_t cnt_off = eo_off + (size_t)E;         // N ints
    const size_t cur_off = cnt_off + (size_t)N;        // N ints
    const size_t rs_off  = cur_off + (size_t)N;        // N+1 ints
    const size_t need_bytes = (rs_off + (size_t)N + 1) * 4 + 256;

    if (ws_size >= need_bytes) {
        float* m_buf     = (float*)d_ws + m_off;
        float* trans4    = (float*)d_ws + t_off;
        int*   eord      = (int*)d_ws + eo_off;
        int*   counts    = (int*)d_ws + cnt_off;
        int*   cursor    = (int*)d_ws + cur_off;
        int*   row_start = (int*)d_ws + rs_off;

        hipMemsetAsync(counts, 0, (size_t)N * sizeof(int), stream);

        egc_hist<<<(E + 255) / 256, 256, 0, stream>>>(edge_index, counts, E);

        egc_scan<<<1, 1024, 0, stream>>>(counts, row_start, cursor, N);

        egc_edge_direct<<<(E + 255) / 256, 256, 0, stream>>>(
            coord, node_feat, edge_index, ff_coeff,
            ew1, eb1, ew2, eb2, cw1, cb1, cw2,
            cursor, m_buf, trans4, eord, E);

        egc_node_wave<<<(N + 7) / 8, 256, 0, stream>>>(
            coord, node_feat, m_buf, trans4, eord, row_start,
            nw1, nb1, nw2, nb2, out_node, out_coord, N);
    } else {
        // fallback: atomic scatter path
        float* agg_h  = (float*)d_ws;
        float* agg_c  = agg_h + (size_t)N * 32;
        float* counts = agg_c + (size_t)N * 3;
        hipMemsetAsync(d_ws, 0, (size_t)N * 36 * sizeof(float), stream);

        egc_edge_fb<<<(E + 255) / 256, 256, 0, stream>>>(
            coord, node_feat, edge_index, ff_coeff,
            ew1, eb1, ew2, eb2, cw1, cb1, cw2,
            agg_h, agg_c, counts, E);

        egc_node_fb<<<(N + 255) / 256, 256, 0, stream>>>(
            coord, node_feat, agg_h, agg_c, counts,
            nw1, nb1, nw2, nb2, out_node, out_coord, N);
    }
}

// Round 8
// 742.394 us; speedup vs baseline: 1.1602x; 1.1602x over previous
//
#include <hip/hip_runtime.h>
#include <math.h>

__device__ __forceinline__ float silu_f(float x) {
    return x / (1.0f + __expf(-x));
}

// sin/cos of 2*pi*rev using HW units (input in REVOLUTIONS, fract-reduced).
__device__ __forceinline__ void sincos_2pi_rev(float rev, float& s, float& c) {
#if __has_builtin(__builtin_amdgcn_sinf) && __has_builtin(__builtin_amdgcn_cosf)
    const float fr = rev - floorf(rev);     // v_fract
    s = __builtin_amdgcn_sinf(fr);          // sin(2*pi*fr)
    c = __builtin_amdgcn_cosf(fr);
#else
    const float xp = 6.2831853071795864769f * rev;
    s = sinf(xp); c = cosf(xp);
#endif
}

// ---------------- K_proj: per-node projections ----------------
// Pi[n] = nf[n] @ ew1[0:32,:] + eb1 ; Pj[n] = nf[n] @ ew1[32:64,:]
// 32 lanes per node; weight loads are lane-indexed -> vector loads (L1-hot).
__global__ __launch_bounds__(256) void egc_proj(
    const float* __restrict__ node_feat,
    const float* __restrict__ ew1, const float* __restrict__ eb1,
    float* __restrict__ Pi, float* __restrict__ Pj, int N)
{
    const int tid = threadIdx.x;
    const int l32 = tid & 31;
    const int n = blockIdx.x * 8 + (tid >> 5);
    if (n >= N) return;

    const float nf = node_feat[(size_t)n * 32 + l32];
    float pi = eb1[l32];
    float pj = 0.0f;
    #pragma unroll
    for (int k = 0; k < 32; ++k) {
        const float b = __shfl(nf, k, 32);
        pi = fmaf(b, ew1[k * 32 + l32], pi);
        pj = fmaf(b, ew1[(32 + k) * 32 + l32], pj);
    }
    Pi[(size_t)n * 32 + l32] = pi;
    Pj[(size_t)n * 32 + l32] = pj;
}

// ---------------- K_hist ----------------
__global__ __launch_bounds__(256) void egc_hist(
    const int* __restrict__ idx_i, int* __restrict__ counts, int E)
{
    const int e = blockIdx.x * 256 + threadIdx.x;
    if (e < E) atomicAdd(&counts[idx_i[e]], 1);
}

// ---------------- K_scan: single-WG, 4 elements/thread ----------------
__global__ __launch_bounds__(1024) void egc_scan(
    const int* __restrict__ counts, int* __restrict__ row_start,
    int* __restrict__ cursor, int N)
{
    __shared__ int wsum[16];
    __shared__ int carry_s;
    const int tid = threadIdx.x;
    const int lane = tid & 63, wid = tid >> 6;
    if (tid == 0) carry_s = 0;
    __syncthreads();
    for (int base = 0; base < N; base += 4096) {
        const int i0 = base + tid * 4;
        int v0 = 0, v1 = 0, v2 = 0, v3 = 0;
        if (i0 + 3 < N) {
            const int4 q = *reinterpret_cast<const int4*>(counts + i0);
            v0 = q.x; v1 = q.y; v2 = q.z; v3 = q.w;
        } else {
            if (i0 + 0 < N) v0 = counts[i0 + 0];
            if (i0 + 1 < N) v1 = counts[i0 + 1];
            if (i0 + 2 < N) v2 = counts[i0 + 2];
        }
        const int p1 = v0, p2 = v0 + v1, p3 = v0 + v1 + v2, tot = p3 + v3;
        int incl = tot;
        #pragma unroll
        for (int off = 1; off < 64; off <<= 1) {
            int v = __shfl_up(incl, off, 64);
            if (lane >= off) incl += v;
        }
        if (lane == 63) wsum[wid] = incl;
        __syncthreads();
        if (wid == 0) {
            int v = (lane < 16) ? wsum[lane] : 0;
            int s = v;
            #pragma unroll
            for (int off = 1; off < 16; off <<= 1) {
                int t = __shfl_up(s, off, 64);
                if (lane >= off) s += t;
            }
            if (lane < 16) wsum[lane] = s - v;   // exclusive wave offsets
        }
        __syncthreads();
        const int carry = carry_s;
        const int tb = carry + wsum[wid] + incl - tot;  // thread exclusive base
        if (i0 + 0 < N) { row_start[i0 + 0] = tb;      cursor[i0 + 0] = tb; }
        if (i0 + 1 < N) { row_start[i0 + 1] = tb + p1; cursor[i0 + 1] = tb + p1; }
        if (i0 + 2 < N) { row_start[i0 + 2] = tb + p2; cursor[i0 + 2] = tb + p2; }
        if (i0 + 3 < N) { row_start[i0 + 3] = tb + p3; cursor[i0 + 3] = tb + p3; }
        __syncthreads();
        if (tid == 1023) carry_s = carry + wsum[15] + incl;  // + chunk total
        __syncthreads();
    }
    if (tid == 0) row_start[N] = carry_s;
}

// ---------------- K_scatter: build slot->e map (isolated from compute) ----
__global__ __launch_bounds__(256) void egc_scatter(
    const int* __restrict__ idx_i, int* __restrict__ cursor,
    int* __restrict__ eord, int E)
{
    const int e = blockIdx.x * 256 + threadIdx.x;
    if (e >= E) return;
    const int slot = atomicAdd(&cursor[idx_i[e]], 1);
    eord[slot] = e;
}

// ---------------- K_edge (tier A): projections in, streams out ----------
// Per-edge weights: ew1 rows 64..71 (1KB) + ew2 (4KB) + eb2 + cw1 (4KB)
// + cb1 + cw2  = ~9.4KB, fits scalar K$ -> no per-edge s_load thrash.
__global__ __launch_bounds__(256) void egc_edge_proj(
    const float* __restrict__ coord,
    const int*   __restrict__ edge_index,
    const float* __restrict__ ff_coeff,
    const float* __restrict__ Pi, const float* __restrict__ Pj,
    const float* __restrict__ ew1,
    const float* __restrict__ ew2, const float* __restrict__ eb2,
    const float* __restrict__ cw1, const float* __restrict__ cb1,
    const float* __restrict__ cw2,
    float* __restrict__ m_buf,    // [E,32] e-ordered (streaming)
    float* __restrict__ trans4,   // [E,4]  e-ordered (streaming)
    int E)
{
    const int e = blockIdx.x * 256 + threadIdx.x;
    if (e >= E) return;

    const int i = edge_index[e];
    const int j = edge_index[E + e];

    const float cix = coord[3*(size_t)i+0], ciy = coord[3*(size_t)i+1], ciz = coord[3*(size_t)i+2];
    const float cjx = coord[3*(size_t)j+0], cjy = coord[3*(size_t)j+1], cjz = coord[3*(size_t)j+2];
    const float cdx = cix - cjx, cdy = ciy - cjy, cdz = ciz - cjz;
    const float radial = cdx*cdx + cdy*cdy + cdz*cdz;

    float ff[8];
    #pragma unroll
    for (int k = 0; k < 4; ++k) {
        float s, c;
        sincos_2pi_rev(radial * ff_coeff[k], s, c);
        ff[k]     = c;
        ff[4 + k] = s;
    }

    // acc = Pi[i] + Pj[j]  (layer-1 node terms precomputed; eb1 folded in Pi)
    float acc[32];
    {
        const float4* a4 = reinterpret_cast<const float4*>(Pi + (size_t)i * 32);
        const float4* b4 = reinterpret_cast<const float4*>(Pj + (size_t)j * 32);
        #pragma unroll
        for (int q = 0; q < 8; ++q) {
            const float4 x = a4[q], y = b4[q];
            acc[4*q+0] = x.x + y.x;
            acc[4*q+1] = x.y + y.y;
            acc[4*q+2] = x.z + y.z;
            acc[4*q+3] = x.w + y.w;
        }
    }
    // + ff @ ew1[64:72,:]
    #pragma unroll
    for (int k = 0; k < 8; ++k) {
        const float* wr = ew1 + (64 + k) * 32;
        #pragma unroll
        for (int o = 0; o < 32; ++o)
            acc[o] = fmaf(ff[k], wr[o], acc[o]);
    }

    float m1[32];
    #pragma unroll
    for (int o = 0; o < 32; ++o) m1[o] = silu_f(acc[o]);

    float m[32];
    #pragma unroll
    for (int o = 0; o < 32; ++o) m[o] = eb2[o];
    #pragma unroll
    for (int h = 0; h < 32; ++h) {
        #pragma unroll
        for (int o = 0; o < 32; ++o)
            m[o] = fmaf(m1[h], ew2[h*32 + o], m[o]);
    }
    #pragma unroll
    for (int o = 0; o < 32; ++o) m[o] = silu_f(m[o]);

    float4* mb = reinterpret_cast<float4*>(m_buf + (size_t)e * 32);
    #pragma unroll
    for (int q = 0; q < 8; ++q) {
        float4 v;
        v.x = m[4*q+0]; v.y = m[4*q+1]; v.z = m[4*q+2]; v.w = m[4*q+3];
        mb[q] = v;
    }

    float c1[32];
    #pragma unroll
    for (int o = 0; o < 32; ++o) c1[o] = cb1[o];
    #pragma unroll
    for (int h = 0; h < 32; ++h) {
        #pragma unroll
        for (int o = 0; o < 32; ++o)
            c1[o] = fmaf(m[h], cw1[h*32 + o], c1[o]);
    }
    float w = 0.0f;
    #pragma unroll
    for (int o = 0; o < 32; ++o) w += silu_f(c1[o]) * cw2[o];

    float4 t; t.x = cdx * w; t.y = cdy * w; t.z = cdz * w; t.w = 0.0f;
    *reinterpret_cast<float4*>(trans4 + (size_t)e * 4) = t;
}

// ---------------- K_edge (tier B): full MLP from nf (no proj buffers) ----
__global__ __launch_bounds__(256) void egc_edge_full(
    const float* __restrict__ coord,
    const float* __restrict__ node_feat,
    const int*   __restrict__ edge_index,
    const float* __restrict__ ff_coeff,
    const float* __restrict__ ew1, const float* __restrict__ eb1,
    const float* __restrict__ ew2, const float* __restrict__ eb2,
    const float* __restrict__ cw1, const float* __restrict__ cb1,
    const float* __restrict__ cw2,
    float* __restrict__ m_buf, float* __restrict__ trans4, int E)
{
    const int e = blockIdx.x * 256 + threadIdx.x;
    if (e >= E) return;

    const int i = edge_index[e];
    const int j = edge_index[E + e];

    const float cix = coord[3*(size_t)i+0], ciy = coord[3*(size_t)i+1], ciz = coord[3*(size_t)i+2];
    const float cjx = coord[3*(size_t)j+0], cjy = coord[3*(size_t)j+1], cjz = coord[3*(size_t)j+2];
    const float cdx = cix - cjx, cdy = ciy - cjy, cdz = ciz - cjz;
    const float radial = cdx*cdx + cdy*cdy + cdz*cdz;

    float ff[8];
    #pragma unroll
    for (int k = 0; k < 4; ++k) {
        float s, c;
        sincos_2pi_rev(radial * ff_coeff[k], s, c);
        ff[k] = c; ff[4+k] = s;
    }

    float acc[32];
    #pragma unroll
    for (int o = 0; o < 32; ++o) acc[o] = eb1[o];
    {
        const float4* nfi4 = reinterpret_cast<const float4*>(node_feat + (size_t)i * 32);
        for (int q = 0; q < 8; ++q) {
            float4 v = nfi4[q];
            float xs[4] = {v.x, v.y, v.z, v.w};
            const float* wr = ew1 + q * 4 * 32;
            #pragma unroll
            for (int kk = 0; kk < 4; ++kk)
                #pragma unroll
                for (int o = 0; o < 32; ++o)
                    acc[o] = fmaf(xs[kk], wr[kk*32 + o], acc[o]);
        }
        const float4* nfj4 = reinterpret_cast<const float4*>(node_feat + (size_t)j * 32);
        for (int q = 0; q < 8; ++q) {
            float4 v = nfj4[q];
            float xs[4] = {v.x, v.y, v.z, v.w};
            const float* wr = ew1 + (32 + q * 4) * 32;
            #pragma unroll
            for (int kk = 0; kk < 4; ++kk)
                #pragma unroll
                for (int o = 0; o < 32; ++o)
                    acc[o] = fmaf(xs[kk], wr[kk*32 + o], acc[o]);
        }
        #pragma unroll
        for (int k = 0; k < 8; ++k) {
            const float* wr = ew1 + (64 + k) * 32;
            #pragma unroll
            for (int o = 0; o < 32; ++o)
                acc[o] = fmaf(ff[k], wr[o], acc[o]);
        }
    }
    float m1[32];
    #pragma unroll
    for (int o = 0; o < 32; ++o) m1[o] = silu_f(acc[o]);
    float m[32];
    #pragma unroll
    for (int o = 0; o < 32; ++o) m[o] = eb2[o];
    #pragma unroll
    for (int h = 0; h < 32; ++h)
        #pragma unroll
        for (int o = 0; o < 32; ++o)
            m[o] = fmaf(m1[h], ew2[h*32 + o], m[o]);
    #pragma unroll
    for (int o = 0; o < 32; ++o) m[o] = silu_f(m[o]);

    float4* mb = reinterpret_cast<float4*>(m_buf + (size_t)e * 32);
    #pragma unroll
    for (int q = 0; q < 8; ++q) {
        float4 v;
        v.x = m[4*q+0]; v.y = m[4*q+1]; v.z = m[4*q+2]; v.w = m[4*q+3];
        mb[q] = v;
    }

    float c1[32];
    #pragma unroll
    for (int o = 0; o < 32; ++o) c1[o] = cb1[o];
    #pragma unroll
    for (int h = 0; h < 32; ++h)
        #pragma unroll
        for (int o = 0; o < 32; ++o)
            c1[o] = fmaf(m[h], cw1[h*32 + o], c1[o]);
    float w = 0.0f;
    #pragma unroll
    for (int o = 0; o < 32; ++o) w += silu_f(c1[o]) * cw2[o];

    float4 t; t.x = cdx * w; t.y = cdy * w; t.z = cdz * w; t.w = 0.0f;
    *reinterpret_cast<float4*>(trans4 + (size_t)e * 4) = t;
}

// ---------------- K_node: wave-parallel gather + MLP ----------------
__global__ __launch_bounds__(256) void egc_node_wave(
    const float* __restrict__ coord,
    const float* __restrict__ node_feat,
    const float* __restrict__ m_buf,
    const float* __restrict__ trans4,
    const int*   __restrict__ eord,
    const int*   __restrict__ row_start,
    const float* __restrict__ nw1, const float* __restrict__ nb1,
    const float* __restrict__ nw2, const float* __restrict__ nb2,
    float* __restrict__ out_node, float* __restrict__ out_coord, int N)
{
    const int tid = threadIdx.x;
    const int l32 = tid & 31;
    const int n = blockIdx.x * 8 + (tid >> 5);
    if (n >= N) return;

    const int rs = row_start[n];
    const int re = row_start[n + 1];

    float agg = 0.0f;
    float tr  = 0.0f;
    for (int k = rs; k < re; ++k) {
        const int e = eord[k];                         // broadcast load
        agg += m_buf[(size_t)e * 32 + l32];            // coalesced 128B row
        if (l32 < 3) tr += trans4[(size_t)e * 4 + l32];
    }

    const float nf = node_feat[(size_t)n * 32 + l32];

    float acc = nb1[l32];
    #pragma unroll
    for (int k = 0; k < 32; ++k)
        acc = fmaf(__shfl(nf, k, 32), nw1[k*32 + l32], acc);
    #pragma unroll
    for (int k = 0; k < 32; ++k)
        acc = fmaf(__shfl(agg, k, 32), nw1[(32+k)*32 + l32], acc);
    const float h1 = silu_f(acc);

    float h2 = nb2[l32];
    #pragma unroll
    for (int k = 0; k < 32; ++k)
        h2 = fmaf(__shfl(h1, k, 32), nw2[k*32 + l32], h2);

    out_node[(size_t)n * 32 + l32] = nf + h2;

    if (l32 < 3) {
        const float deg = (float)(re - rs);
        out_coord[(size_t)n * 3 + l32] =
            coord[(size_t)n * 3 + l32] + tr / fmaxf(deg, 1.0f);
    }
}

// ---------------- tier C fallback: atomic scatter ----------------
__global__ __launch_bounds__(256) void egc_edge_fb(
    const float* __restrict__ coord,
    const float* __restrict__ node_feat,
    const int*   __restrict__ edge_index,
    const float* __restrict__ ff_coeff,
    const float* __restrict__ ew1, const float* __restrict__ eb1,
    const float* __restrict__ ew2, const float* __restrict__ eb2,
    const float* __restrict__ cw1, const float* __restrict__ cb1,
    const float* __restrict__ cw2,
    float* __restrict__ agg_h, float* __restrict__ agg_c, float* __restrict__ counts,
    int E)
{
    const int e = blockIdx.x * 256 + threadIdx.x;
    if (e >= E) return;
    const int i = edge_index[e];
    const int j = edge_index[E + e];

    const float cix = coord[3*(size_t)i+0], ciy = coord[3*(size_t)i+1], ciz = coord[3*(size_t)i+2];
    const float cjx = coord[3*(size_t)j+0], cjy = coord[3*(size_t)j+1], cjz = coord[3*(size_t)j+2];
    const float cdx = cix - cjx, cdy = ciy - cjy, cdz = ciz - cjz;
    const float radial = cdx*cdx + cdy*cdy + cdz*cdz;

    float ff[8];
    #pragma unroll
    for (int k = 0; k < 4; ++k) {
        float s, c;
        sincos_2pi_rev(radial * ff_coeff[k], s, c);
        ff[k] = c; ff[4+k] = s;
    }
    float acc[32];
    #pragma unroll
    for (int o = 0; o < 32; ++o) acc[o] = eb1[o];
    {
        const float4* nfi4 = reinterpret_cast<const float4*>(node_feat + (size_t)i * 32);
        for (int q = 0; q < 8; ++q) {
            float4 v = nfi4[q];
            float xs[4] = {v.x, v.y, v.z, v.w};
            const float* wr = ew1 + q * 4 * 32;
            #pragma unroll
            for (int kk = 0; kk < 4; ++kk)
                #pragma unroll
                for (int o = 0; o < 32; ++o)
                    acc[o] = fmaf(xs[kk], wr[kk*32 + o], acc[o]);
        }
        const float4* nfj4 = reinterpret_cast<const float4*>(node_feat + (size_t)j * 32);
        for (int q = 0; q < 8; ++q) {
            float4 v = nfj4[q];
            float xs[4] = {v.x, v.y, v.z, v.w};
            const float* wr = ew1 + (32 + q * 4) * 32;
            #pragma unroll
            for (int kk = 0; kk < 4; ++kk)
                #pragma unroll
                for (int o = 0; o < 32; ++o)
                    acc[o] = fmaf(xs[kk], wr[kk*32 + o], acc[o]);
        }
        #pragma unroll
        for (int k = 0; k < 8; ++k) {
            const float* wr = ew1 + (64 + k) * 32;
            #pragma unroll
            for (int o = 0; o < 32; ++o)
                acc[o] = fmaf(ff[k], wr[o], acc[o]);
        }
    }
    float m1[32];
    #pragma unroll
    for (int o = 0; o < 32; ++o) m1[o] = silu_f(acc[o]);
    float m[32];
    #pragma unroll
    for (int o = 0; o < 32; ++o) m[o] = eb2[o];
    #pragma unroll
    for (int h = 0; h < 32; ++h)
        #pragma unroll
        for (int o = 0; o < 32; ++o)
            m[o] = fmaf(m1[h], ew2[h*32 + o], m[o]);
    #pragma unroll
    for (int o = 0; o < 32; ++o) m[o] = silu_f(m[o]);

    float* dst = agg_h + (size_t)i * 32;
    #pragma unroll
    for (int o = 0; o < 32; ++o) atomicAdd(&dst[o], m[o]);

    float c1[32];
    #pragma unroll
    for (int o = 0; o < 32; ++o) c1[o] = cb1[o];
    #pragma unroll
    for (int h = 0; h < 32; ++h)
        #pragma unroll
        for (int o = 0; o < 32; ++o)
            c1[o] = fmaf(m[h], cw1[h*32 + o], c1[o]);
    float w = 0.0f;
    #pragma unroll
    for (int o = 0; o < 32; ++o) w += silu_f(c1[o]) * cw2[o];

    atomicAdd(&agg_c[(size_t)i*3 + 0], cdx * w);
    atomicAdd(&agg_c[(size_t)i*3 + 1], cdy * w);
    atomicAdd(&agg_c[(size_t)i*3 + 2], cdz * w);
    atomicAdd(&counts[i], 1.0f);
}

__global__ __launch_bounds__(256) void egc_node_fb(
    const float* __restrict__ coord,
    const float* __restrict__ node_feat,
    const float* __restrict__ agg_h,
    const float* __restrict__ agg_c,
    const float* __restrict__ counts,
    const float* __restrict__ nw1, const float* __restrict__ nb1,
    const float* __restrict__ nw2, const float* __restrict__ nb2,
    float* __restrict__ out_node, float* __restrict__ out_coord, int N)
{
    const int tid = threadIdx.x;
    const int l32 = tid & 31;
    const int n = blockIdx.x * 8 + (tid >> 5);
    if (n >= N) return;

    const float nf  = node_feat[(size_t)n * 32 + l32];
    const float agg = agg_h[(size_t)n * 32 + l32];

    float acc = nb1[l32];
    #pragma unroll
    for (int k = 0; k < 32; ++k)
        acc = fmaf(__shfl(nf, k, 32), nw1[k*32 + l32], acc);
    #pragma unroll
    for (int k = 0; k < 32; ++k)
        acc = fmaf(__shfl(agg, k, 32), nw1[(32+k)*32 + l32], acc);
    const float h1 = silu_f(acc);

    float h2 = nb2[l32];
    #pragma unroll
    for (int k = 0; k < 32; ++k)
        h2 = fmaf(__shfl(h1, k, 32), nw2[k*32 + l32], h2);

    out_node[(size_t)n * 32 + l32] = nf + h2;

    if (l32 < 3) {
        const float cnt = fmaxf(counts[n], 1.0f);
        out_coord[(size_t)n * 3 + l32] =
            coord[(size_t)n * 3 + l32] + agg_c[(size_t)n * 3 + l32] / cnt;
    }
}

// ================= launch =================

extern "C" void kernel_launch(void* const* d_in, const int* in_sizes, int n_in,
                              void* d_out, int out_size, void* d_ws, size_t ws_size,
                              hipStream_t stream) {
    const float* coord     = (const float*)d_in[0];
    const float* node_feat = (const float*)d_in[1];
    const int*   edge_index= (const int*)  d_in[2];
    const float* ff_coeff  = (const float*)d_in[3];
    const float* ew1 = (const float*)d_in[4];
    const float* eb1 = (const float*)d_in[5];
    const float* ew2 = (const float*)d_in[6];
    const float* eb2 = (const float*)d_in[7];
    const float* cw1 = (const float*)d_in[8];
    const float* cb1 = (const float*)d_in[9];
    const float* cw2 = (const float*)d_in[10];
    const float* nw1 = (const float*)d_in[11];
    const float* nb1 = (const float*)d_in[12];
    const float* nw2 = (const float*)d_in[13];
    const float* nb2 = (const float*)d_in[14];

    const int N = in_sizes[0] / 3;   // coord [N,3]
    const int E = in_sizes[2] / 2;   // edge_index [2,E]

    float* out_node  = (float*)d_out;             // [N,32]
    float* out_coord = out_node + (size_t)N * 32; // [N,3]

    // workspace layout (element offsets, 16B-aligned regions)
    const size_t m_off   = 0;                          // E*32 f
    const size_t t_off   = m_off + (size_t)E * 32;     // E*4 f
    const size_t eo_off  = t_off + (size_t)E * 4;      // E i
    const size_t cnt_off = eo_off + (size_t)E;         // N i
    const size_t cur_off = cnt_off + (size_t)N;        // N i
    const size_t rs_off  = cur_off + (size_t)N;        // N+1 i
    const size_t pi_off  = (rs_off + (size_t)N + 1 + 3) & ~(size_t)3;  // N*32 f
    const size_t pj_off  = pi_off + (size_t)N * 32;    // N*32 f
    const size_t need_A  = (pj_off + (size_t)N * 32) * 4 + 256;
    const size_t need_B  = (rs_off + (size_t)N + 1) * 4 + 256;

    if (ws_size >= need_B) {
        float* m_buf     = (float*)d_ws + m_off;
        float* trans4    = (float*)d_ws + t_off;
        int*   eord      = (int*)d_ws + eo_off;
        int*   counts    = (int*)d_ws + cnt_off;
        int*   cursor    = (int*)d_ws + cur_off;
        int*   row_start = (int*)d_ws + rs_off;

        hipMemsetAsync(counts, 0, (size_t)N * sizeof(int), stream);

        egc_hist<<<(E + 255) / 256, 256, 0, stream>>>(edge_index, counts, E);
        egc_scan<<<1, 1024, 0, stream>>>(counts, row_start, cursor, N);
        egc_scatter<<<(E + 255) / 256, 256, 0, stream>>>(edge_index, cursor, eord, E);

        if (ws_size >= need_A) {
            float* Pi = (float*)d_ws + pi_off;
            float* Pj = (float*)d_ws + pj_off;
            egc_proj<<<(N + 7) / 8, 256, 0, stream>>>(node_feat, ew1, eb1, Pi, Pj, N);
            egc_edge_proj<<<(E + 255) / 256, 256, 0, stream>>>(
                coord, edge_index, ff_coeff, Pi, Pj,
                ew1, ew2, eb2, cw1, cb1, cw2, m_buf, trans4, E);
        } else {
            egc_edge_full<<<(E + 255) / 256, 256, 0, stream>>>(
                coord, node_feat, edge_index, ff_coeff,
                ew1, eb1, ew2, eb2, cw1, cb1, cw2, m_buf, trans4, E);
        }

        egc_node_wave<<<(N + 7) / 8, 256, 0, stream>>>(
            coord, node_feat, m_buf, trans4, eord, row_start,
            nw1, nb1, nw2, nb2, out_node, out_coord, N);
    } else {
        // tier C: atomic fallback
        float* agg_h  = (float*)d_ws;
        float* agg_c  = agg_h + (size_t)N * 32;
        float* counts = agg_c + (size_t)N * 3;
        hipMemsetAsync(d_ws, 0, (size_t)N * 36 * sizeof(float), stream);

        egc_edge_fb<<<(E + 255) / 256, 256, 0, stream>>>(
            coord, node_feat, edge_index, ff_coeff,
            ew1, eb1, ew2, eb2, cw1, cb1, cw2,
            agg_h, agg_c, counts, E);

        egc_node_fb<<<(N + 7) / 8, 256, 0, stream>>>(
            coord, node_feat, agg_h, agg_c, counts,
            nw1, nb1, nw2, nb2, out_node, out_coord, N);
    }
}

// Round 9
// 728.018 us; speedup vs baseline: 1.1831x; 1.0197x over previous
//
#include <hip/hip_runtime.h>
#include <math.h>

__device__ __forceinline__ float silu_f(float x) {
    return x / (1.0f + __expf(-x));
}

// sin/cos of 2*pi*rev using HW units (input in REVOLUTIONS, fract-reduced).
__device__ __forceinline__ void sincos_2pi_rev(float rev, float& s, float& c) {
#if __has_builtin(__builtin_amdgcn_sinf) && __has_builtin(__builtin_amdgcn_cosf)
    const float fr = rev - floorf(rev);     // v_fract
    s = __builtin_amdgcn_sinf(fr);          // sin(2*pi*fr)
    c = __builtin_amdgcn_cosf(fr);
#else
    const float xp = 6.2831853071795864769f * rev;
    s = sinf(xp); c = cosf(xp);
#endif
}

typedef float v4f __attribute__((ext_vector_type(4)));

__device__ __forceinline__ void nt_store4(float* p, float a, float b, float c, float d) {
    v4f v = {a, b, c, d};
    __builtin_nontemporal_store(v, reinterpret_cast<v4f*>(p));
}
__device__ __forceinline__ float nt_loadf(const float* p) {
    return __builtin_nontemporal_load(p);
}

// ---------------- K_proj: per-node projections ----------------
// Pi[n] = nf[n] @ ew1[0:32,:] + eb1 ; Pj[n] = nf[n] @ ew1[32:64,:]
__global__ __launch_bounds__(256) void egc_proj(
    const float* __restrict__ node_feat,
    const float* __restrict__ ew1, const float* __restrict__ eb1,
    float* __restrict__ Pi, float* __restrict__ Pj, int N)
{
    const int tid = threadIdx.x;
    const int l32 = tid & 31;
    const int n = blockIdx.x * 8 + (tid >> 5);
    if (n >= N) return;

    const float nf = node_feat[(size_t)n * 32 + l32];
    float pi = eb1[l32];
    float pj = 0.0f;
    #pragma unroll
    for (int k = 0; k < 32; ++k) {
        const float b = __shfl(nf, k, 32);
        pi = fmaf(b, ew1[k * 32 + l32], pi);
        pj = fmaf(b, ew1[(32 + k) * 32 + l32], pj);
    }
    Pi[(size_t)n * 32 + l32] = pi;
    Pj[(size_t)n * 32 + l32] = pj;
}

// ---------------- K_hist: int4-vectorized ----------------
__global__ __launch_bounds__(256) void egc_hist(
    const int* __restrict__ idx_i, int* __restrict__ counts, int E)
{
    const int t = blockIdx.x * 256 + threadIdx.x;
    const int e0 = t * 4;
    if (e0 + 3 < E) {
        const int4 q = *reinterpret_cast<const int4*>(idx_i + e0);
        atomicAdd(&counts[q.x], 1);
        atomicAdd(&counts[q.y], 1);
        atomicAdd(&counts[q.z], 1);
        atomicAdd(&counts[q.w], 1);
    } else {
        for (int e = e0; e < E; ++e) atomicAdd(&counts[idx_i[e]], 1);
    }
}

// ---------------- K_scan: single-WG, 4 elements/thread ----------------
__global__ __launch_bounds__(1024) void egc_scan(
    const int* __restrict__ counts, int* __restrict__ row_start,
    int* __restrict__ cursor, int N)
{
    __shared__ int wsum[16];
    __shared__ int carry_s;
    const int tid = threadIdx.x;
    const int lane = tid & 63, wid = tid >> 6;
    if (tid == 0) carry_s = 0;
    __syncthreads();
    for (int base = 0; base < N; base += 4096) {
        const int i0 = base + tid * 4;
        int v0 = 0, v1 = 0, v2 = 0, v3 = 0;
        if (i0 + 3 < N) {
            const int4 q = *reinterpret_cast<const int4*>(counts + i0);
            v0 = q.x; v1 = q.y; v2 = q.z; v3 = q.w;
        } else {
            if (i0 + 0 < N) v0 = counts[i0 + 0];
            if (i0 + 1 < N) v1 = counts[i0 + 1];
            if (i0 + 2 < N) v2 = counts[i0 + 2];
        }
        const int p1 = v0, p2 = v0 + v1, p3 = v0 + v1 + v2, tot = p3 + v3;
        int incl = tot;
        #pragma unroll
        for (int off = 1; off < 64; off <<= 1) {
            int v = __shfl_up(incl, off, 64);
            if (lane >= off) incl += v;
        }
        if (lane == 63) wsum[wid] = incl;
        __syncthreads();
        if (wid == 0) {
            int v = (lane < 16) ? wsum[lane] : 0;
            int s = v;
            #pragma unroll
            for (int off = 1; off < 16; off <<= 1) {
                int t = __shfl_up(s, off, 64);
                if (lane >= off) s += t;
            }
            if (lane < 16) wsum[lane] = s - v;   // exclusive wave offsets
        }
        __syncthreads();
        const int carry = carry_s;
        const int tb = carry + wsum[wid] + incl - tot;  // thread exclusive base
        if (i0 + 0 < N) { row_start[i0 + 0] = tb;      cursor[i0 + 0] = tb; }
        if (i0 + 1 < N) { row_start[i0 + 1] = tb + p1; cursor[i0 + 1] = tb + p1; }
        if (i0 + 2 < N) { row_start[i0 + 2] = tb + p2; cursor[i0 + 2] = tb + p2; }
        if (i0 + 3 < N) { row_start[i0 + 3] = tb + p3; cursor[i0 + 3] = tb + p3; }
        __syncthreads();
        if (tid == 1023) carry_s = carry + wsum[15] + incl;  // + chunk total
        __syncthreads();
    }
    if (tid == 0) row_start[N] = carry_s;
}

// ---------------- K_edge (tier A): proj inputs; slot-claim fused ----------
// Atomic slot claim issued at top, consumed only at the eord store ->
// latency hidden under ~2.4K MACs. m/trans written e-ordered with
// NON-TEMPORAL stores so the streaming output doesn't evict Pi/Pj from L3.
__global__ __launch_bounds__(256) void egc_edge_proj(
    const float* __restrict__ coord,
    const int*   __restrict__ edge_index,
    const float* __restrict__ ff_coeff,
    const float* __restrict__ Pi, const float* __restrict__ Pj,
    const float* __restrict__ ew1,
    const float* __restrict__ ew2, const float* __restrict__ eb2,
    const float* __restrict__ cw1, const float* __restrict__ cb1,
    const float* __restrict__ cw2,
    int*   __restrict__ cursor,   // [N] pre-init to row_start
    float* __restrict__ m_buf,    // [E,32] e-ordered
    float* __restrict__ trans3,   // [E,3]  e-ordered
    int*   __restrict__ eord,     // [E] slot -> e
    int E)
{
    const int e = blockIdx.x * 256 + threadIdx.x;
    if (e >= E) return;

    const int i = edge_index[e];
    const int j = edge_index[E + e];
    const int slot = atomicAdd(&cursor[i], 1);   // hidden under MLP below

    const float cix = coord[3*(size_t)i+0], ciy = coord[3*(size_t)i+1], ciz = coord[3*(size_t)i+2];
    const float cjx = coord[3*(size_t)j+0], cjy = coord[3*(size_t)j+1], cjz = coord[3*(size_t)j+2];
    const float cdx = cix - cjx, cdy = ciy - cjy, cdz = ciz - cjz;
    const float radial = cdx*cdx + cdy*cdy + cdz*cdz;

    float ff[8];
    #pragma unroll
    for (int k = 0; k < 4; ++k) {
        float s, c;
        sincos_2pi_rev(radial * ff_coeff[k], s, c);
        ff[k]     = c;
        ff[4 + k] = s;
    }

    // acc = Pi[i] + Pj[j]  (layer-1 node terms precomputed; eb1 in Pi)
    float acc[32];
    {
        const float4* a4 = reinterpret_cast<const float4*>(Pi + (size_t)i * 32);
        const float4* b4 = reinterpret_cast<const float4*>(Pj + (size_t)j * 32);
        #pragma unroll
        for (int q = 0; q < 8; ++q) {
            const float4 x = a4[q], y = b4[q];
            acc[4*q+0] = x.x + y.x;
            acc[4*q+1] = x.y + y.y;
            acc[4*q+2] = x.z + y.z;
            acc[4*q+3] = x.w + y.w;
        }
    }
    #pragma unroll
    for (int k = 0; k < 8; ++k) {
        const float* wr = ew1 + (64 + k) * 32;
        #pragma unroll
        for (int o = 0; o < 32; ++o)
            acc[o] = fmaf(ff[k], wr[o], acc[o]);
    }

    float m1[32];
    #pragma unroll
    for (int o = 0; o < 32; ++o) m1[o] = silu_f(acc[o]);

    float m[32];
    #pragma unroll
    for (int o = 0; o < 32; ++o) m[o] = eb2[o];
    #pragma unroll
    for (int h = 0; h < 32; ++h) {
        #pragma unroll
        for (int o = 0; o < 32; ++o)
            m[o] = fmaf(m1[h], ew2[h*32 + o], m[o]);
    }
    #pragma unroll
    for (int o = 0; o < 32; ++o) m[o] = silu_f(m[o]);

    float* mb = m_buf + (size_t)e * 32;
    #pragma unroll
    for (int q = 0; q < 8; ++q)
        nt_store4(mb + 4*q, m[4*q+0], m[4*q+1], m[4*q+2], m[4*q+3]);

    float c1[32];
    #pragma unroll
    for (int o = 0; o < 32; ++o) c1[o] = cb1[o];
    #pragma unroll
    for (int h = 0; h < 32; ++h) {
        #pragma unroll
        for (int o = 0; o < 32; ++o)
            c1[o] = fmaf(m[h], cw1[h*32 + o], c1[o]);
    }
    float w = 0.0f;
    #pragma unroll
    for (int o = 0; o < 32; ++o) w += silu_f(c1[o]) * cw2[o];

    float* tp = trans3 + (size_t)e * 3;
    __builtin_nontemporal_store(cdx * w, tp + 0);
    __builtin_nontemporal_store(cdy * w, tp + 1);
    __builtin_nontemporal_store(cdz * w, tp + 2);

    eord[slot] = e;   // scattered 4B into 6.4MB (L2-resident)
}

// ---------------- K_edge (tier B): full MLP, slot-claim fused ----------
__global__ __launch_bounds__(256) void egc_edge_full(
    const float* __restrict__ coord,
    const float* __restrict__ node_feat,
    const int*   __restrict__ edge_index,
    const float* __restrict__ ff_coeff,
    const float* __restrict__ ew1, const float* __restrict__ eb1,
    const float* __restrict__ ew2, const float* __restrict__ eb2,
    const float* __restrict__ cw1, const float* __restrict__ cb1,
    const float* __restrict__ cw2,
    int* __restrict__ cursor,
    float* __restrict__ m_buf, float* __restrict__ trans3,
    int* __restrict__ eord, int E)
{
    const int e = blockIdx.x * 256 + threadIdx.x;
    if (e >= E) return;

    const int i = edge_index[e];
    const int j = edge_index[E + e];
    const int slot = atomicAdd(&cursor[i], 1);

    const float cix = coord[3*(size_t)i+0], ciy = coord[3*(size_t)i+1], ciz = coord[3*(size_t)i+2];
    const float cjx = coord[3*(size_t)j+0], cjy = coord[3*(size_t)j+1], cjz = coord[3*(size_t)j+2];
    const float cdx = cix - cjx, cdy = ciy - cjy, cdz = ciz - cjz;
    const float radial = cdx*cdx + cdy*cdy + cdz*cdz;

    float ff[8];
    #pragma unroll
    for (int k = 0; k < 4; ++k) {
        float s, c;
        sincos_2pi_rev(radial * ff_coeff[k], s, c);
        ff[k] = c; ff[4+k] = s;
    }

    float acc[32];
    #pragma unroll
    for (int o = 0; o < 32; ++o) acc[o] = eb1[o];
    {
        const float4* nfi4 = reinterpret_cast<const float4*>(node_feat + (size_t)i * 32);
        for (int q = 0; q < 8; ++q) {
            float4 v = nfi4[q];
            float xs[4] = {v.x, v.y, v.z, v.w};
            const float* wr = ew1 + q * 4 * 32;
            #pragma unroll
            for (int kk = 0; kk < 4; ++kk)
                #pragma unroll
                for (int o = 0; o < 32; ++o)
                    acc[o] = fmaf(xs[kk], wr[kk*32 + o], acc[o]);
        }
        const float4* nfj4 = reinterpret_cast<const float4*>(node_feat + (size_t)j * 32);
        for (int q = 0; q < 8; ++q) {
            float4 v = nfj4[q];
            float xs[4] = {v.x, v.y, v.z, v.w};
            const float* wr = ew1 + (32 + q * 4) * 32;
            #pragma unroll
            for (int kk = 0; kk < 4; ++kk)
                #pragma unroll
                for (int o = 0; o < 32; ++o)
                    acc[o] = fmaf(xs[kk], wr[kk*32 + o], acc[o]);
        }
        #pragma unroll
        for (int k = 0; k < 8; ++k) {
            const float* wr = ew1 + (64 + k) * 32;
            #pragma unroll
            for (int o = 0; o < 32; ++o)
                acc[o] = fmaf(ff[k], wr[o], acc[o]);
        }
    }
    float m1[32];
    #pragma unroll
    for (int o = 0; o < 32; ++o) m1[o] = silu_f(acc[o]);
    float m[32];
    #pragma unroll
    for (int o = 0; o < 32; ++o) m[o] = eb2[o];
    #pragma unroll
    for (int h = 0; h < 32; ++h)
        #pragma unroll
        for (int o = 0; o < 32; ++o)
            m[o] = fmaf(m1[h], ew2[h*32 + o], m[o]);
    #pragma unroll
    for (int o = 0; o < 32; ++o) m[o] = silu_f(m[o]);

    float* mb = m_buf + (size_t)e * 32;
    #pragma unroll
    for (int q = 0; q < 8; ++q)
        nt_store4(mb + 4*q, m[4*q+0], m[4*q+1], m[4*q+2], m[4*q+3]);

    float c1[32];
    #pragma unroll
    for (int o = 0; o < 32; ++o) c1[o] = cb1[o];
    #pragma unroll
    for (int h = 0; h < 32; ++h)
        #pragma unroll
        for (int o = 0; o < 32; ++o)
            c1[o] = fmaf(m[h], cw1[h*32 + o], c1[o]);
    float w = 0.0f;
    #pragma unroll
    for (int o = 0; o < 32; ++o) w += silu_f(c1[o]) * cw2[o];

    float* tp = trans3 + (size_t)e * 3;
    __builtin_nontemporal_store(cdx * w, tp + 0);
    __builtin_nontemporal_store(cdy * w, tp + 1);
    __builtin_nontemporal_store(cdz * w, tp + 2);

    eord[slot] = e;
}

// ---------------- K_node: wave-parallel gather (2-way ILP) + MLP --------
__global__ __launch_bounds__(256) void egc_node_wave(
    const float* __restrict__ coord,
    const float* __restrict__ node_feat,
    const float* __restrict__ m_buf,
    const float* __restrict__ trans3,
    const int*   __restrict__ eord,
    const int*   __restrict__ row_start,
    const float* __restrict__ nw1, const float* __restrict__ nb1,
    const float* __restrict__ nw2, const float* __restrict__ nb2,
    float* __restrict__ out_node, float* __restrict__ out_coord, int N)
{
    const int tid = threadIdx.x;
    const int l32 = tid & 31;
    const int n = blockIdx.x * 8 + (tid >> 5);
    if (n >= N) return;

    const int rs = row_start[n];
    const int re = row_start[n + 1];

    float agg = 0.0f;
    float tr  = 0.0f;
    int k = rs;
    for (; k + 2 <= re; k += 2) {           // 2 chains in flight
        const int e0 = eord[k];
        const int e1 = eord[k + 1];
        const float a0 = nt_loadf(m_buf + (size_t)e0 * 32 + l32);
        const float a1 = nt_loadf(m_buf + (size_t)e1 * 32 + l32);
        agg += a0 + a1;
        if (l32 < 3)
            tr += nt_loadf(trans3 + (size_t)e0 * 3 + l32)
                + nt_loadf(trans3 + (size_t)e1 * 3 + l32);
    }
    if (k < re) {
        const int e0 = eord[k];
        agg += nt_loadf(m_buf + (size_t)e0 * 32 + l32);
        if (l32 < 3) tr += nt_loadf(trans3 + (size_t)e0 * 3 + l32);
    }

    const float nf = node_feat[(size_t)n * 32 + l32];

    float acc = nb1[l32];
    #pragma unroll
    for (int kk = 0; kk < 32; ++kk)
        acc = fmaf(__shfl(nf, kk, 32), nw1[kk*32 + l32], acc);
    #pragma unroll
    for (int kk = 0; kk < 32; ++kk)
        acc = fmaf(__shfl(agg, kk, 32), nw1[(32+kk)*32 + l32], acc);
    const float h1 = silu_f(acc);

    float h2 = nb2[l32];
    #pragma unroll
    for (int kk = 0; kk < 32; ++kk)
        h2 = fmaf(__shfl(h1, kk, 32), nw2[kk*32 + l32], h2);

    out_node[(size_t)n * 32 + l32] = nf + h2;

    if (l32 < 3) {
        const float deg = (float)(re - rs);
        out_coord[(size_t)n * 3 + l32] =
            coord[(size_t)n * 3 + l32] + tr / fmaxf(deg, 1.0f);
    }
}

// ---------------- tier C fallback: atomic scatter ----------------
__global__ __launch_bounds__(256) void egc_edge_fb(
    const float* __restrict__ coord,
    const float* __restrict__ node_feat,
    const int*   __restrict__ edge_index,
    const float* __restrict__ ff_coeff,
    const float* __restrict__ ew1, const float* __restrict__ eb1,
    const float* __restrict__ ew2, const float* __restrict__ eb2,
    const float* __restrict__ cw1, const float* __restrict__ cb1,
    const float* __restrict__ cw2,
    float* __restrict__ agg_h, float* __restrict__ agg_c, float* __restrict__ counts,
    int E)
{
    const int e = blockIdx.x * 256 + threadIdx.x;
    if (e >= E) return;
    const int i = edge_index[e];
    const int j = edge_index[E + e];

    const float cix = coord[3*(size_t)i+0], ciy = coord[3*(size_t)i+1], ciz = coord[3*(size_t)i+2];
    const float cjx = coord[3*(size_t)j+0], cjy = coord[3*(size_t)j+1], cjz = coord[3*(size_t)j+2];
    const float cdx = cix - cjx, cdy = ciy - cjy, cdz = ciz - cjz;
    const float radial = cdx*cdx + cdy*cdy + cdz*cdz;

    float ff[8];
    #pragma unroll
    for (int k = 0; k < 4; ++k) {
        float s, c;
        sincos_2pi_rev(radial * ff_coeff[k], s, c);
        ff[k] = c; ff[4+k] = s;
    }
    float acc[32];
    #pragma unroll
    for (int o = 0; o < 32; ++o) acc[o] = eb1[o];
    {
        const float4* nfi4 = reinterpret_cast<const float4*>(node_feat + (size_t)i * 32);
        for (int q = 0; q < 8; ++q) {
            float4 v = nfi4[q];
            float xs[4] = {v.x, v.y, v.z, v.w};
            const float* wr = ew1 + q * 4 * 32;
            #pragma unroll
            for (int kk = 0; kk < 4; ++kk)
                #pragma unroll
                for (int o = 0; o < 32; ++o)
                    acc[o] = fmaf(xs[kk], wr[kk*32 + o], acc[o]);
        }
        const float4* nfj4 = reinterpret_cast<const float4*>(node_feat + (size_t)j * 32);
        for (int q = 0; q < 8; ++q) {
            float4 v = nfj4[q];
            float xs[4] = {v.x, v.y, v.z, v.w};
            const float* wr = ew1 + (32 + q * 4) * 32;
            #pragma unroll
            for (int kk = 0; kk < 4; ++kk)
                #pragma unroll
                for (int o = 0; o < 32; ++o)
                    acc[o] = fmaf(xs[kk], wr[kk*32 + o], acc[o]);
        }
        #pragma unroll
        for (int k = 0; k < 8; ++k) {
            const float* wr = ew1 + (64 + k) * 32;
            #pragma unroll
            for (int o = 0; o < 32; ++o)
                acc[o] = fmaf(ff[k], wr[o], acc[o]);
        }
    }
    float m1[32];
    #pragma unroll
    for (int o = 0; o < 32; ++o) m1[o] = silu_f(acc[o]);
    float m[32];
    #pragma unroll
    for (int o = 0; o < 32; ++o) m[o] = eb2[o];
    #pragma unroll
    for (int h = 0; h < 32; ++h)
        #pragma unroll
        for (int o = 0; o < 32; ++o)
            m[o] = fmaf(m1[h], ew2[h*32 + o], m[o]);
    #pragma unroll
    for (int o = 0; o < 32; ++o) m[o] = silu_f(m[o]);

    float* dst = agg_h + (size_t)i * 32;
    #pragma unroll
    for (int o = 0; o < 32; ++o) atomicAdd(&dst[o], m[o]);

    float c1[32];
    #pragma unroll
    for (int o = 0; o < 32; ++o) c1[o] = cb1[o];
    #pragma unroll
    for (int h = 0; h < 32; ++h)
        #pragma unroll
        for (int o = 0; o < 32; ++o)
            c1[o] = fmaf(m[h], cw1[h*32 + o], c1[o]);
    float w = 0.0f;
    #pragma unroll
    for (int o = 0; o < 32; ++o) w += silu_f(c1[o]) * cw2[o];

    atomicAdd(&agg_c[(size_t)i*3 + 0], cdx * w);
    atomicAdd(&agg_c[(size_t)i*3 + 1], cdy * w);
    atomicAdd(&agg_c[(size_t)i*3 + 2], cdz * w);
    atomicAdd(&counts[i], 1.0f);
}

__global__ __launch_bounds__(256) void egc_node_fb(
    const float* __restrict__ coord,
    const float* __restrict__ node_feat,
    const float* __restrict__ agg_h,
    const float* __restrict__ agg_c,
    const float* __restrict__ counts,
    const float* __restrict__ nw1, const float* __restrict__ nb1,
    const float* __restrict__ nw2, const float* __restrict__ nb2,
    float* __restrict__ out_node, float* __restrict__ out_coord, int N)
{
    const int tid = threadIdx.x;
    const int l32 = tid & 31;
    const int n = blockIdx.x * 8 + (tid >> 5);
    if (n >= N) return;

    const float nf  = node_feat[(size_t)n * 32 + l32];
    const float agg = agg_h[(size_t)n * 32 + l32];

    float acc = nb1[l32];
    #pragma unroll
    for (int k = 0; k < 32; ++k)
        acc = fmaf(__shfl(nf, k, 32), nw1[k*32 + l32], acc);
    #pragma unroll
    for (int k = 0; k < 32; ++k)
        acc = fmaf(__shfl(agg, k, 32), nw1[(32+k)*32 + l32], acc);
    const float h1 = silu_f(acc);

    float h2 = nb2[l32];
    #pragma unroll
    for (int k = 0; k < 32; ++k)
        h2 = fmaf(__shfl(h1, k, 32), nw2[k*32 + l32], h2);

    out_node[(size_t)n * 32 + l32] = nf + h2;

    if (l32 < 3) {
        const float cnt = fmaxf(counts[n], 1.0f);
        out_coord[(size_t)n * 3 + l32] =
            coord[(size_t)n * 3 + l32] + agg_c[(size_t)n * 3 + l32] / cnt;
    }
}

// ================= launch =================

extern "C" void kernel_launch(void* const* d_in, const int* in_sizes, int n_in,
                              void* d_out, int out_size, void* d_ws, size_t ws_size,
                              hipStream_t stream) {
    const float* coord     = (const float*)d_in[0];
    const float* node_feat = (const float*)d_in[1];
    const int*   edge_index= (const int*)  d_in[2];
    const float* ff_coeff  = (const float*)d_in[3];
    const float* ew1 = (const float*)d_in[4];
    const float* eb1 = (const float*)d_in[5];
    const float* ew2 = (const float*)d_in[6];
    const float* eb2 = (const float*)d_in[7];
    const float* cw1 = (const float*)d_in[8];
    const float* cb1 = (const float*)d_in[9];
    const float* cw2 = (const float*)d_in[10];
    const float* nw1 = (const float*)d_in[11];
    const float* nb1 = (const float*)d_in[12];
    const float* nw2 = (const float*)d_in[13];
    const float* nb2 = (const float*)d_in[14];

    const int N = in_sizes[0] / 3;   // coord [N,3]
    const int E = in_sizes[2] / 2;   // edge_index [2,E]

    float* out_node  = (float*)d_out;             // [N,32]
    float* out_coord = out_node + (size_t)N * 32; // [N,3]

    // workspace layout (element offsets, 16B-aligned regions)
    const size_t m_off   = 0;                           // E*32 f
    const size_t t_off   = m_off + (size_t)E * 32;      // E*3 f
    const size_t eo_off  = (t_off + (size_t)E * 3 + 3) & ~(size_t)3;  // E i
    const size_t cnt_off = eo_off + (size_t)E;          // N i
    const size_t cur_off = cnt_off + (size_t)N;         // N i
    const size_t rs_off  = cur_off + (size_t)N;         // N+1 i
    const size_t pi_off  = (rs_off + (size_t)N + 1 + 3) & ~(size_t)3;  // N*32 f
    const size_t pj_off  = pi_off + (size_t)N * 32;     // N*32 f
    const size_t need_A  = (pj_off + (size_t)N * 32) * 4 + 256;
    const size_t need_B  = (rs_off + (size_t)N + 1) * 4 + 256;

    if (ws_size >= need_B) {
        float* m_buf     = (float*)d_ws + m_off;
        float* trans3    = (float*)d_ws + t_off;
        int*   eord      = (int*)d_ws + eo_off;
        int*   counts    = (int*)d_ws + cnt_off;
        int*   cursor    = (int*)d_ws + cur_off;
        int*   row_start = (int*)d_ws + rs_off;

        hipMemsetAsync(counts, 0, (size_t)N * sizeof(int), stream);

        egc_hist<<<(E / 4 + 256) / 256, 256, 0, stream>>>(edge_index, counts, E);
        egc_scan<<<1, 1024, 0, stream>>>(counts, row_start, cursor, N);

        if (ws_size >= need_A) {
            float* Pi = (float*)d_ws + pi_off;
            float* Pj = (float*)d_ws + pj_off;
            egc_proj<<<(N + 7) / 8, 256, 0, stream>>>(node_feat, ew1, eb1, Pi, Pj, N);
            egc_edge_proj<<<(E + 255) / 256, 256, 0, stream>>>(
                coord, edge_index, ff_coeff, Pi, Pj,
                ew1, ew2, eb2, cw1, cb1, cw2,
                cursor, m_buf, trans3, eord, E);
        } else {
            egc_edge_full<<<(E + 255) / 256, 256, 0, stream>>>(
                coord, node_feat, edge_index, ff_coeff,
                ew1, eb1, ew2, eb2, cw1, cb1, cw2,
                cursor, m_buf, trans3, eord, E);
        }

        egc_node_wave<<<(N + 7) / 8, 256, 0, stream>>>(
            coord, node_feat, m_buf, trans3, eord, row_start,
            nw1, nb1, nw2, nb2, out_node, out_coord, N);
    } else {
        // tier C: atomic fallback
        float* agg_h  = (float*)d_ws;
        float* agg_c  = agg_h + (size_t)N * 32;
        float* counts = agg_c + (size_t)N * 3;
        hipMemsetAsync(d_ws, 0, (size_t)N * 36 * sizeof(float), stream);

        egc_edge_fb<<<(E + 255) / 256, 256, 0, stream>>>(
            coord, node_feat, edge_index, ff_coeff,
            ew1, eb1, ew2, eb2, cw1, cb1, cw2,
            agg_h, agg_c, counts, E);

        egc_node_fb<<<(N + 7) / 8, 256, 0, stream>>>(
            coord, node_feat, agg_h, agg_c, counts,
            nw1, nb1, nw2, nb2, out_node, out_coord, N);
    }
}